// Round 3
// baseline (66.858 us; speedup 1.0000x reference)
//
#include <hip/hip_runtime.h>
#include <hip/hip_fp16.h>

#define K_EPSILON 0.0001f

constexpr int N = 4, K = 8, H = 256, W = 256, C = 64;
constexpr int NSLICE = 4, SC = 16;  // 4 slices x 16 channels

// ---------------------------------------------------------------------------
// Pre-pass 1: fold mask + denom into packed u32 per (pixel, k):
//   bits[16:0] = safe index, bits[31:17] = round(32767 * alpha/max(den,eps))
// ---------------------------------------------------------------------------
__global__ __launch_bounds__(256) void pack_weights(
    const int* __restrict__ frag, const float* __restrict__ alpha,
    uint32_t* __restrict__ packed) {
  const int p = blockIdx.x * 256 + threadIdx.x;  // pixel 0..N*H*W-1
  const int n = p >> 16, hw = p & 65535;
  float a[K];
  int id[K];
  float den = 0.0f;
  #pragma unroll
  for (int k = 0; k < K; ++k) {
    size_t g = ((size_t)(n * K + k) << 16) + hw;
    int idx = frag[g];
    float av = alpha[g];
    bool m = idx >= 0;
    id[k] = m ? idx : 0;
    a[k] = m ? av : 0.0f;
    den += a[k];
  }
  float inv = 1.0f / fmaxf(den, K_EPSILON);
  uint32_t pk[K];
  #pragma unroll
  for (int k = 0; k < K; ++k) {
    uint32_t wq = (uint32_t)rintf(a[k] * inv * 32767.0f);  // w in [0,1]
    pk[k] = (wq << 17) | (uint32_t)id[k];
  }
  uint4* dst = (uint4*)&packed[(size_t)p * 8];
  dst[0] = make_uint4(pk[0], pk[1], pk[2], pk[3]);
  dst[1] = make_uint4(pk[4], pk[5], pk[6], pk[7]);
}

// ---------------------------------------------------------------------------
// Pre-pass 2: transpose ptclds (C=64,P) fp32 -> slice-major fp16:
//   dst[((s*P + p)*8 + j] (half2) holds channels (16s+2j, 16s+2j+1) of point p.
//   One slice = P*16*2B = 3.2MB -> fits one XCD's 4MiB L2.
// ---------------------------------------------------------------------------
__global__ __launch_bounds__(256) void transpose_slices(
    const float* __restrict__ src, __half2* __restrict__ dst, int P) {
  __shared__ float tile[64][65];
  const int t = threadIdx.x;
  const int p0 = blockIdx.x * 64;
  const int lane = t & 63, quad = t >> 6;

  #pragma unroll
  for (int i = 0; i < 16; ++i) {
    int c = quad * 16 + i;
    int p = p0 + lane;
    tile[lane][c] = (p < P) ? src[(size_t)c * P + p] : 0.0f;
  }
  __syncthreads();

  const int j = t & 7;        // half2 slot within slice
  const int lp0 = t >> 3;     // 0..31
  #pragma unroll
  for (int s = 0; s < NSLICE; ++s) {
    #pragma unroll
    for (int half = 0; half < 2; ++half) {
      int lp = lp0 + half * 32;
      int p = p0 + lp;
      int c2 = s * 8 + j;
      if (p < P)
        dst[((size_t)s * P + p) * 8 + j] =
            __floats2half2_rn(tile[lp][2 * c2], tile[lp][2 * c2 + 1]);
    }
  }
}

// ---------------------------------------------------------------------------
// Main: one block = one (n,h) row (256 pixels) x one 16-channel slice.
// Block->slice chosen so slice s lands on XCDs {2s,2s+1} (round-robin %8):
// the 3.2MB slice table stays L2-resident per XCD.
// Wave: 8 pixels x 8 lanes; lane j holds channels (2j,2j+1) via half2 gather.
// Packed words distributed one-per-lane, broadcast via __shfl.
// ---------------------------------------------------------------------------
__global__ __launch_bounds__(256) void compositor_sliced(
    const uint32_t* __restrict__ packed, const __half2* __restrict__ table,
    float* __restrict__ out, int P) {
  __shared__ float s_out[256][SC + 1];  // stride 17: conflict-free
  const int t = threadIdx.x;
  const int B = blockIdx.x;
  const int xcd = B & 7;
  const int slice = xcd >> 1;
  const int rowid = ((B >> 3) << 1) | (B & 1);  // 0..1023
  const int n = rowid >> 8, h = rowid & 255;
  const size_t p0 = (size_t)rowid << 8;

  const __half2* tab = table + (size_t)slice * P * 8;
  const int lane = t & 63, wid = t >> 6;
  const int pg = lane >> 3, j = lane & 7;
  const float invq = 1.0f / 32767.0f;

  #pragma unroll 2
  for (int iter = 0; iter < 8; ++iter) {
    int pix = iter * 32 + wid * 8 + pg;
    // lane l holds packed k-slot (l&7) of pixel (iter*32+wid*8+(l>>3))
    uint32_t mine = packed[p0 * 8 + (size_t)iter * 256 + wid * 64 + lane];
    float acc0 = 0.0f, acc1 = 0.0f;
    #pragma unroll
    for (int k = 0; k < K; ++k) {
      uint32_t v = __shfl(mine, (lane & 56) + k, 64);
      int idx = (int)(v & 0x1FFFF);
      float w = (float)(v >> 17) * invq;
      float2 f = __half22float2(tab[(size_t)idx * 8 + j]);
      acc0 += w * f.x;
      acc1 += w * f.y;
    }
    s_out[pix][2 * j]     = acc0;
    s_out[pix][2 * j + 1] = acc1;
  }
  __syncthreads();

  #pragma unroll
  for (int i = 0; i < SC; ++i) {
    int c = slice * SC + i;
    out[(((size_t)(n * C + c)) << 16) + ((size_t)h << 8) + t] = s_out[t][i];
  }
}

// ---------------------------------------------------------------------------
// Fallback (workspace too small): fp32 strided gather, known-correct from R1.
// ---------------------------------------------------------------------------
__global__ __launch_bounds__(256) void compositor_fallback(
    const int* __restrict__ frag, const float* __restrict__ alpha,
    const float* __restrict__ pt, float* __restrict__ out, int P) {
  __shared__ int   s_idx[K][64];
  __shared__ float s_a[K][64];
  __shared__ float s_out[64][67];

  const int t = threadIdx.x;
  const int tile = blockIdx.x;
  const int w0 = (tile & 3) * 64;
  const int h = (tile >> 2) & (H - 1);
  const int n = tile >> 10;

  #pragma unroll
  for (int i = 0; i < 2; ++i) {
    int f = t + i * 256;
    int k = f >> 6, wo = f & 63;
    size_t g = (((size_t)(n * K + k) * H + h) * W) + w0 + wo;
    s_idx[k][wo] = frag[g];
    s_a[k][wo]   = alpha[g];
  }
  __syncthreads();

  const int lane = t & 63;
  const int wid  = t >> 6;
  for (int jj = 0; jj < 16; ++jj) {
    int pix = wid * 16 + jj;
    float acc = 0.0f, den = 0.0f;
    #pragma unroll
    for (int k = 0; k < K; ++k) {
      int idx = s_idx[k][pix];
      float a = s_a[k][pix];
      if (idx < 0) a = 0.0f;
      int safe = idx < 0 ? 0 : idx;
      acc += a * pt[(size_t)lane * P + safe];
      den += a;
    }
    s_out[pix][lane] = acc / fmaxf(den, K_EPSILON);
  }
  __syncthreads();

  #pragma unroll
  for (int i = 0; i < 16; ++i) {
    int c = (t >> 6) + i * 4;
    int wo = t & 63;
    size_t g = (((size_t)(n * C + c) * H + h) * W) + w0 + wo;
    out[g] = s_out[wo][c];
  }
}

extern "C" void kernel_launch(void* const* d_in, const int* in_sizes, int n_in,
                              void* d_out, int out_size, void* d_ws, size_t ws_size,
                              hipStream_t stream) {
  const int*   frag   = (const int*)d_in[0];
  const float* alpha  = (const float*)d_in[1];
  const float* ptclds = (const float*)d_in[2];
  float*       out    = (float*)d_out;

  const int P = in_sizes[2] / C;  // 100000
  const size_t tableBytes  = (size_t)P * C * sizeof(__half);         // 12.8 MB
  const size_t packedBytes = (size_t)N * H * W * K * sizeof(uint32_t);  // 8 MB

  if (ws_size >= tableBytes + packedBytes) {
    __half2*  ptT    = (__half2*)d_ws;
    uint32_t* packed = (uint32_t*)((char*)d_ws + tableBytes);

    pack_weights<<<(N * H * W) / 256, 256, 0, stream>>>(frag, alpha, packed);
    transpose_slices<<<(P + 63) / 64, 256, 0, stream>>>(ptclds, ptT, P);
    compositor_sliced<<<NSLICE * N * H, 256, 0, stream>>>(packed, ptT, out, P);
  } else {
    compositor_fallback<<<N * H * (W / 64), 256, 0, stream>>>(frag, alpha,
                                                              ptclds, out, P);
  }
}

// Round 4
// 64.353 us; speedup vs baseline: 1.0389x; 1.0389x over previous
//
#include <hip/hip_runtime.h>
#include <hip/hip_fp16.h>

#define K_EPSILON 0.0001f

constexpr int N = 4, K = 8, H = 256, W = 256, C = 64;
constexpr int NSLICE = 4, SC = 16;  // 4 slices x 16 channels

// ---------------------------------------------------------------------------
// Pre-pass: transpose ptclds (C=64,P) fp32 -> slice-major fp16:
//   dst[(s*P + p)*8 + j] (half2) = channels (16s+2j, 16s+2j+1) of point p.
//   One slice = P*16*2B = 3.2MB -> fits one XCD's 4MiB L2.
// Block = 16 channels x 256 points: 1KB-coalesced reads, coalesced writes.
// ---------------------------------------------------------------------------
__global__ __launch_bounds__(256) void transpose_slices2(
    const float* __restrict__ src, __half2* __restrict__ dst, int P, int PB) {
  __shared__ float tile[16][260];  // pad 4: 2-way max on both phases
  const int t = threadIdx.x;
  const int s = blockIdx.x / PB;
  const int p0 = (blockIdx.x - s * PB) * 256;

  #pragma unroll
  for (int i = 0; i < 16; ++i) {
    int c = s * SC + i;
    int p = p0 + t;
    tile[i][t] = (p < P) ? src[(size_t)c * P + p] : 0.0f;
  }
  __syncthreads();

  const int j = t & 7;     // half2 slot (channels 2j, 2j+1 of slice)
  const int pp0 = t >> 3;  // 0..31
  #pragma unroll
  for (int i = 0; i < 8; ++i) {
    int pp = pp0 + i * 32;
    int p = p0 + pp;
    if (p < P)
      dst[((size_t)s * P + p) * 8 + j] =
          __floats2half2_rn(tile[2 * j][pp], tile[2 * j + 1][pp]);
  }
}

// ---------------------------------------------------------------------------
// Fused main: one block = one (n,h) row (256 pixels) x one 16-channel slice.
// Block->slice chosen so slice s lands on XCDs {2s,2s+1} (round-robin %8):
// the 3.2MB slice table stays L2-resident per XCD (R3: FETCH 108->45MB).
//
// Phase 1 (pack): thread t owns pixel t; loads frag/alpha across K, folds
//   mask + 1/max(den,eps) into packed u32 (idx | w<<17) in padded LDS.
// Phase 2 (gather): wave = 8 pixels x 8 lanes, lane j = channels (2j,2j+1),
//   half2 gathers; fully unrolled -> 64 independent loads in flight.
// Phase 3: coalesced channel-plane writes via padded LDS.
// ---------------------------------------------------------------------------
__global__ __launch_bounds__(256) void compositor_fused(
    const int* __restrict__ frag, const float* __restrict__ alpha,
    const __half2* __restrict__ table, float* __restrict__ out, int P) {
  __shared__ uint32_t s_pk[256][9];    // pad 9: broadcast reads conflict-free
  __shared__ float    s_out[256][SC + 1];
  const int t = threadIdx.x;
  const int B = blockIdx.x;
  const int slice = (B & 7) >> 1;
  const int rowid = ((B >> 3) << 1) | (B & 1);  // 0..1023, bijective
  const int n = rowid >> 8, h = rowid & 255;

  // ---- Phase 1: pack ----
  {
    float a[K];
    int id[K];
    float den = 0.0f;
    #pragma unroll
    for (int k = 0; k < K; ++k) {
      size_t g = (((size_t)(n * K + k)) << 16) + ((size_t)h << 8) + t;
      int idx = frag[g];
      float av = alpha[g];
      bool m = idx >= 0;
      id[k] = m ? idx : 0;
      a[k] = m ? av : 0.0f;
      den += a[k];
    }
    float inv = 1.0f / fmaxf(den, K_EPSILON);
    #pragma unroll
    for (int k = 0; k < K; ++k) {
      uint32_t wq = (uint32_t)rintf(a[k] * inv * 32767.0f);
      s_pk[t][k] = (wq << 17) | (uint32_t)id[k];
    }
  }
  __syncthreads();

  // ---- Phase 2: gather ----
  const __half2* tab = table + (size_t)slice * P * 8;
  const int lane = t & 63, wid = t >> 6;
  const int pg = lane >> 3, j = lane & 7;
  const float invq = 1.0f / 32767.0f;

  #pragma unroll
  for (int iter = 0; iter < 8; ++iter) {
    int pix = iter * 32 + wid * 8 + pg;
    float acc0 = 0.0f, acc1 = 0.0f;
    #pragma unroll
    for (int k = 0; k < K; ++k) {
      uint32_t v = s_pk[pix][k];   // 8-lane broadcast, conflict-free
      int idx = (int)(v & 0x1FFFF);
      float w = (float)(v >> 17) * invq;
      float2 f = __half22float2(tab[(size_t)idx * 8 + j]);
      acc0 += w * f.x;
      acc1 += w * f.y;
    }
    s_out[pix][2 * j]     = acc0;
    s_out[pix][2 * j + 1] = acc1;
  }
  __syncthreads();

  // ---- Phase 3: coalesced output ----
  #pragma unroll
  for (int i = 0; i < SC; ++i) {
    int c = slice * SC + i;
    out[(((size_t)(n * C + c)) << 16) + ((size_t)h << 8) + t] = s_out[t][i];
  }
}

// ---------------------------------------------------------------------------
// Fallback (workspace too small): fp32 strided gather, known-correct from R1.
// ---------------------------------------------------------------------------
__global__ __launch_bounds__(256) void compositor_fallback(
    const int* __restrict__ frag, const float* __restrict__ alpha,
    const float* __restrict__ pt, float* __restrict__ out, int P) {
  __shared__ int   s_idx[K][64];
  __shared__ float s_a[K][64];
  __shared__ float s_out[64][67];

  const int t = threadIdx.x;
  const int tile = blockIdx.x;
  const int w0 = (tile & 3) * 64;
  const int h = (tile >> 2) & (H - 1);
  const int n = tile >> 10;

  #pragma unroll
  for (int i = 0; i < 2; ++i) {
    int f = t + i * 256;
    int k = f >> 6, wo = f & 63;
    size_t g = (((size_t)(n * K + k) * H + h) * W) + w0 + wo;
    s_idx[k][wo] = frag[g];
    s_a[k][wo]   = alpha[g];
  }
  __syncthreads();

  const int lane = t & 63;
  const int wid  = t >> 6;
  for (int jj = 0; jj < 16; ++jj) {
    int pix = wid * 16 + jj;
    float acc = 0.0f, den = 0.0f;
    #pragma unroll
    for (int k = 0; k < K; ++k) {
      int idx = s_idx[k][pix];
      float a = s_a[k][pix];
      if (idx < 0) a = 0.0f;
      int safe = idx < 0 ? 0 : idx;
      acc += a * pt[(size_t)lane * P + safe];
      den += a;
    }
    s_out[pix][lane] = acc / fmaxf(den, K_EPSILON);
  }
  __syncthreads();

  #pragma unroll
  for (int i = 0; i < 16; ++i) {
    int c = (t >> 6) + i * 4;
    int wo = t & 63;
    size_t g = (((size_t)(n * C + c) * H + h) * W) + w0 + wo;
    out[g] = s_out[wo][c];
  }
}

extern "C" void kernel_launch(void* const* d_in, const int* in_sizes, int n_in,
                              void* d_out, int out_size, void* d_ws, size_t ws_size,
                              hipStream_t stream) {
  const int*   frag   = (const int*)d_in[0];
  const float* alpha  = (const float*)d_in[1];
  const float* ptclds = (const float*)d_in[2];
  float*       out    = (float*)d_out;

  const int P = in_sizes[2] / C;  // 100000
  const size_t tableBytes = (size_t)P * C * sizeof(__half);  // 12.8 MB

  if (ws_size >= tableBytes) {
    __half2* ptT = (__half2*)d_ws;
    const int PB = (P + 255) / 256;
    transpose_slices2<<<NSLICE * PB, 256, 0, stream>>>(ptclds, ptT, P, PB);
    compositor_fused<<<NSLICE * N * H, 256, 0, stream>>>(frag, alpha, ptT, out, P);
  } else {
    compositor_fallback<<<N * H * (W / 64), 256, 0, stream>>>(frag, alpha,
                                                              ptclds, out, P);
  }
}

// Round 5
// 57.777 us; speedup vs baseline: 1.1572x; 1.1138x over previous
//
#include <hip/hip_runtime.h>
#include <hip/hip_fp16.h>

#define K_EPSILON 0.0001f

constexpr int N = 4, K = 8, H = 256, W = 256, C = 64;

// ---------------------------------------------------------------------------
// Pre-pass: transpose ptclds (C=64,P) fp32 -> (P,64) fp16, 128B per point.
// Block = 32 channels x 256 points. Reads 1KB-coalesced, writes 64B segments.
// ---------------------------------------------------------------------------
__global__ __launch_bounds__(256) void transpose_pt(
    const float* __restrict__ src, __half2* __restrict__ dst, int P, int PB) {
  __shared__ float tile[32][257];
  const int t = threadIdx.x;
  const int cb = blockIdx.x / PB;           // 0..1 (channel half)
  const int p0 = (blockIdx.x - cb * PB) * 256;

  #pragma unroll
  for (int i = 0; i < 32; ++i) {
    int c = cb * 32 + i;
    int p = p0 + t;
    tile[i][t] = (p < P) ? src[(size_t)c * P + p] : 0.0f;
  }
  __syncthreads();

  const int jj = t & 15;    // half2 slot within 32-ch half
  const int pl0 = t >> 4;   // 0..15
  #pragma unroll
  for (int i = 0; i < 16; ++i) {
    int pl = pl0 + i * 16;
    int p = p0 + pl;
    if (p < P)
      dst[(size_t)p * 32 + cb * 16 + jj] =
          __floats2half2_rn(tile[2 * jj][pl], tile[2 * jj + 1][pl]);
  }
}

// ---------------------------------------------------------------------------
// Fused main: one block = 128 pixels (half a (n,h) row), 256 threads.
// Phase 1 (pack, threads 0..127): pixel t's 8 (idx,w) folded with mask and
//   1/max(den,eps) into packed u32 (idx | wq<<17) in LDS.
// Phase 2 (gather): wave = 8 pixels x 8 lanes; lane j loads uint4 = 16B =
//   channels [8j,8j+8) of the pixel -> 1KB per wave-instr in full lines,
//   8 K-gathers fully unrolled (8KB in flight per wave). fp32 accumulate.
// Phase 3: coalesced channel-plane stores via LDS [128][65] (odd stride).
// ---------------------------------------------------------------------------
__global__ __launch_bounds__(256, 4) void compositor_wide(
    const int* __restrict__ frag, const float* __restrict__ alpha,
    const __half2* __restrict__ table, float* __restrict__ out, int P) {
  __shared__ uint32_t s_pk[128][9];
  __shared__ float    s_out[128][65];

  const int t = threadIdx.x;
  const int B = blockIdx.x;           // 0..2047
  const int rowid = B >> 1;           // 0..1023
  const int n = rowid >> 8, h = rowid & 255;
  const int w0 = (B & 1) * 128;

  // ---- Phase 1: pack (threads 0..127, one pixel each) ----
  if (t < 128) {
    float a[K];
    int id[K];
    float den = 0.0f;
    #pragma unroll
    for (int k = 0; k < K; ++k) {
      size_t g = (((size_t)(n * K + k)) << 16) + ((size_t)h << 8) + w0 + t;
      int idx = frag[g];
      float av = alpha[g];
      bool m = idx >= 0;
      id[k] = m ? idx : 0;
      a[k] = m ? av : 0.0f;
      den += a[k];
    }
    float inv = 1.0f / fmaxf(den, K_EPSILON);
    #pragma unroll
    for (int k = 0; k < K; ++k) {
      uint32_t wq = (uint32_t)rintf(a[k] * inv * 32767.0f);
      s_pk[t][k] = (wq << 17) | (uint32_t)id[k];
    }
  }
  __syncthreads();

  // ---- Phase 2: wide gather ----
  const char* tb = (const char*)table;  // (P,64) half, 128B per point
  const int lane = t & 63, wid = t >> 6;
  const int pg = lane >> 3;   // pixel within wave-group
  const int j = lane & 3 ? (lane & 7) : (lane & 7);  // lane & 7
  const int jc = lane & 7;
  const float invq = 1.0f / 32767.0f;

  #pragma unroll
  for (int iter = 0; iter < 4; ++iter) {
    int pix = iter * 32 + wid * 8 + pg;
    float acc0 = 0.f, acc1 = 0.f, acc2 = 0.f, acc3 = 0.f;
    float acc4 = 0.f, acc5 = 0.f, acc6 = 0.f, acc7 = 0.f;
    #pragma unroll
    for (int k = 0; k < K; ++k) {
      uint32_t v = s_pk[pix][k];            // 8-lane same-address broadcast
      int idx = (int)(v & 0x1FFFF);
      float w = (float)(v >> 17) * invq;
      uint4 d = *(const uint4*)(tb + ((size_t)idx << 7) + (jc << 4));
      float2 f0 = __half22float2(*(const __half2*)&d.x);
      float2 f1 = __half22float2(*(const __half2*)&d.y);
      float2 f2 = __half22float2(*(const __half2*)&d.z);
      float2 f3 = __half22float2(*(const __half2*)&d.w);
      acc0 += w * f0.x; acc1 += w * f0.y;
      acc2 += w * f1.x; acc3 += w * f1.y;
      acc4 += w * f2.x; acc5 += w * f2.y;
      acc6 += w * f3.x; acc7 += w * f3.y;
    }
    float* row = &s_out[pix][8 * jc];
    row[0] = acc0; row[1] = acc1; row[2] = acc2; row[3] = acc3;
    row[4] = acc4; row[5] = acc5; row[6] = acc6; row[7] = acc7;
  }
  __syncthreads();

  // ---- Phase 3: coalesced output (128 px per c-plane = 512B runs) ----
  const int w = t & 127, chalf = t >> 7;
  #pragma unroll
  for (int i = 0; i < 32; ++i) {
    int c = i * 2 + chalf;
    out[(((size_t)(n * C + c)) << 16) + ((size_t)h << 8) + w0 + w] =
        s_out[w][c];
  }
}

// ---------------------------------------------------------------------------
// Fallback (workspace too small): fp32 strided gather, known-correct from R1.
// ---------------------------------------------------------------------------
__global__ __launch_bounds__(256) void compositor_fallback(
    const int* __restrict__ frag, const float* __restrict__ alpha,
    const float* __restrict__ pt, float* __restrict__ out, int P) {
  __shared__ int   s_idx[K][64];
  __shared__ float s_a[K][64];
  __shared__ float s_out[64][67];

  const int t = threadIdx.x;
  const int tile = blockIdx.x;
  const int w0 = (tile & 3) * 64;
  const int h = (tile >> 2) & (H - 1);
  const int n = tile >> 10;

  #pragma unroll
  for (int i = 0; i < 2; ++i) {
    int f = t + i * 256;
    int k = f >> 6, wo = f & 63;
    size_t g = (((size_t)(n * K + k) * H + h) * W) + w0 + wo;
    s_idx[k][wo] = frag[g];
    s_a[k][wo]   = alpha[g];
  }
  __syncthreads();

  const int lane = t & 63;
  const int wid  = t >> 6;
  for (int jj = 0; jj < 16; ++jj) {
    int pix = wid * 16 + jj;
    float acc = 0.0f, den = 0.0f;
    #pragma unroll
    for (int k = 0; k < K; ++k) {
      int idx = s_idx[k][pix];
      float a = s_a[k][pix];
      if (idx < 0) a = 0.0f;
      int safe = idx < 0 ? 0 : idx;
      acc += a * pt[(size_t)lane * P + safe];
      den += a;
    }
    s_out[pix][lane] = acc / fmaxf(den, K_EPSILON);
  }
  __syncthreads();

  #pragma unroll
  for (int i = 0; i < 16; ++i) {
    int c = (t >> 6) + i * 4;
    int wo = t & 63;
    size_t g = (((size_t)(n * C + c) * H + h) * W) + w0 + wo;
    out[g] = s_out[wo][c];
  }
}

extern "C" void kernel_launch(void* const* d_in, const int* in_sizes, int n_in,
                              void* d_out, int out_size, void* d_ws, size_t ws_size,
                              hipStream_t stream) {
  const int*   frag   = (const int*)d_in[0];
  const float* alpha  = (const float*)d_in[1];
  const float* ptclds = (const float*)d_in[2];
  float*       out    = (float*)d_out;

  const int P = in_sizes[2] / C;  // 100000
  const size_t tableBytes = (size_t)P * C * sizeof(__half);  // 12.8 MB

  if (ws_size >= tableBytes) {
    __half2* ptT = (__half2*)d_ws;
    const int PB = (P + 255) / 256;  // 391
    transpose_pt<<<2 * PB, 256, 0, stream>>>(ptclds, ptT, P, PB);
    compositor_wide<<<2 * N * H, 256, 0, stream>>>(frag, alpha, ptT, out, P);
  } else {
    compositor_fallback<<<N * H * (W / 64), 256, 0, stream>>>(frag, alpha,
                                                              ptclds, out, P);
  }
}

// Round 6
// 57.564 us; speedup vs baseline: 1.1615x; 1.0037x over previous
//
#include <hip/hip_runtime.h>
#include <hip/hip_fp16.h>

#define K_EPSILON 0.0001f

constexpr int N = 4, K = 8, H = 256, W = 256, C = 64;

// ---------------------------------------------------------------------------
// Pre-pass: transpose ptclds (C=64,P) fp32 -> (P,64) fp16, 128B per point.
// Block = 32 channels x 256 points. Reads 1KB-coalesced, writes 64B segments.
// ---------------------------------------------------------------------------
__global__ __launch_bounds__(256) void transpose_pt(
    const float* __restrict__ src, __half2* __restrict__ dst, int P, int PB) {
  __shared__ float tile[32][257];
  const int t = threadIdx.x;
  const int cb = blockIdx.x / PB;           // 0..1 (channel half)
  const int p0 = (blockIdx.x - cb * PB) * 256;

  #pragma unroll
  for (int i = 0; i < 32; ++i) {
    int c = cb * 32 + i;
    int p = p0 + t;
    tile[i][t] = (p < P) ? src[(size_t)c * P + p] : 0.0f;
  }
  __syncthreads();

  const int jj = t & 15;    // half2 slot within 32-ch half
  const int pl0 = t >> 4;   // 0..15
  #pragma unroll
  for (int i = 0; i < 16; ++i) {
    int pl = pl0 + i * 16;
    int p = p0 + pl;
    if (p < P)
      dst[(size_t)p * 32 + cb * 16 + jj] =
          __floats2half2_rn(tile[2 * jj][pl], tile[2 * jj + 1][pl]);
  }
}

// ---------------------------------------------------------------------------
// Fused main: one block = 128 pixels (half a (n,h) row), 256 threads.
// Phase 1 (pack, threads 0..127): fold mask + 1/max(den,eps) into packed
//   u32 (idx | wq<<17) in LDS.
// Phase 2 (gather): wave = 8 pixels x 8 lanes; lane jc loads uint4 = 16B =
//   channels [8jc,8jc+8) -> 1KB/wave-instr in full 64B lines, 8 K-gathers
//   fully unrolled. fp32 accumulate, results staged as half2 (LDS diet:
//   33KB->17KB => 7 blocks/CU instead of 4; occupancy was the R5 limiter).
// Phase 3: coalesced channel-plane stores.
// ---------------------------------------------------------------------------
__global__ __launch_bounds__(256, 7) void compositor_wide(
    const int* __restrict__ frag, const float* __restrict__ alpha,
    const __half2* __restrict__ table, float* __restrict__ out, int P) {
  __shared__ uint32_t s_pk[128][9];      // 4.6 KB
  __shared__ __half2  s_out[128][33];    // 16.9 KB, odd stride
  const int t = threadIdx.x;
  const int B = blockIdx.x;           // 0..2047
  const int rowid = B >> 1;           // 0..1023
  const int n = rowid >> 8, h = rowid & 255;
  const int w0 = (B & 1) * 128;

  // ---- Phase 1: pack (threads 0..127, one pixel each) ----
  if (t < 128) {
    float a[K];
    int id[K];
    float den = 0.0f;
    #pragma unroll
    for (int k = 0; k < K; ++k) {
      size_t g = (((size_t)(n * K + k)) << 16) + ((size_t)h << 8) + w0 + t;
      int idx = frag[g];
      float av = alpha[g];
      bool m = idx >= 0;
      id[k] = m ? idx : 0;
      a[k] = m ? av : 0.0f;
      den += a[k];
    }
    float inv = 1.0f / fmaxf(den, K_EPSILON);
    #pragma unroll
    for (int k = 0; k < K; ++k) {
      uint32_t wq = (uint32_t)rintf(a[k] * inv * 32767.0f);
      s_pk[t][k] = (wq << 17) | (uint32_t)id[k];
    }
  }
  __syncthreads();

  // ---- Phase 2: wide gather ----
  const char* tb = (const char*)table;  // (P,64) half, 128B per point
  const int lane = t & 63, wid = t >> 6;
  const int pg = lane >> 3;   // pixel within wave-group
  const int jc = lane & 7;    // 16B chunk = channels [8jc, 8jc+8)
  const float invq = 1.0f / 32767.0f;

  #pragma unroll
  for (int iter = 0; iter < 4; ++iter) {
    int pix = iter * 32 + wid * 8 + pg;
    float acc0 = 0.f, acc1 = 0.f, acc2 = 0.f, acc3 = 0.f;
    float acc4 = 0.f, acc5 = 0.f, acc6 = 0.f, acc7 = 0.f;
    #pragma unroll
    for (int k = 0; k < K; ++k) {
      uint32_t v = s_pk[pix][k];            // 8-lane same-address broadcast
      int idx = (int)(v & 0x1FFFF);
      float w = (float)(v >> 17) * invq;
      uint4 d = *(const uint4*)(tb + ((size_t)idx << 7) + (jc << 4));
      float2 f0 = __half22float2(*(const __half2*)&d.x);
      float2 f1 = __half22float2(*(const __half2*)&d.y);
      float2 f2 = __half22float2(*(const __half2*)&d.z);
      float2 f3 = __half22float2(*(const __half2*)&d.w);
      acc0 += w * f0.x; acc1 += w * f0.y;
      acc2 += w * f1.x; acc3 += w * f1.y;
      acc4 += w * f2.x; acc5 += w * f2.y;
      acc6 += w * f3.x; acc7 += w * f3.y;
    }
    __half2* row = &s_out[pix][4 * jc];
    row[0] = __floats2half2_rn(acc0, acc1);
    row[1] = __floats2half2_rn(acc2, acc3);
    row[2] = __floats2half2_rn(acc4, acc5);
    row[3] = __floats2half2_rn(acc6, acc7);
  }
  __syncthreads();

  // ---- Phase 3: coalesced output (128 px runs = 512B per c-plane) ----
  const int w = t & 127, hh = t >> 7;   // hh: which 16 half2-slots
  const size_t base = ((size_t)h << 8) + w0 + w;
  #pragma unroll
  for (int ii = 0; ii < 16; ++ii) {
    int i = hh * 16 + ii;               // half2 slot 0..31 -> channels 2i,2i+1
    float2 f = __half22float2(s_out[w][i]);
    out[(((size_t)(n * C + 2 * i)) << 16) + base]     = f.x;
    out[(((size_t)(n * C + 2 * i + 1)) << 16) + base] = f.y;
  }
}

// ---------------------------------------------------------------------------
// Fallback (workspace too small): fp32 strided gather, known-correct from R1.
// ---------------------------------------------------------------------------
__global__ __launch_bounds__(256) void compositor_fallback(
    const int* __restrict__ frag, const float* __restrict__ alpha,
    const float* __restrict__ pt, float* __restrict__ out, int P) {
  __shared__ int   s_idx[K][64];
  __shared__ float s_a[K][64];
  __shared__ float s_out[64][67];

  const int t = threadIdx.x;
  const int tile = blockIdx.x;
  const int w0 = (tile & 3) * 64;
  const int h = (tile >> 2) & (H - 1);
  const int n = tile >> 10;

  #pragma unroll
  for (int i = 0; i < 2; ++i) {
    int f = t + i * 256;
    int k = f >> 6, wo = f & 63;
    size_t g = (((size_t)(n * K + k) * H + h) * W) + w0 + wo;
    s_idx[k][wo] = frag[g];
    s_a[k][wo]   = alpha[g];
  }
  __syncthreads();

  const int lane = t & 63;
  const int wid  = t >> 6;
  for (int jj = 0; jj < 16; ++jj) {
    int pix = wid * 16 + jj;
    float acc = 0.0f, den = 0.0f;
    #pragma unroll
    for (int k = 0; k < K; ++k) {
      int idx = s_idx[k][pix];
      float a = s_a[k][pix];
      if (idx < 0) a = 0.0f;
      int safe = idx < 0 ? 0 : idx;
      acc += a * pt[(size_t)lane * P + safe];
      den += a;
    }
    s_out[pix][lane] = acc / fmaxf(den, K_EPSILON);
  }
  __syncthreads();

  #pragma unroll
  for (int i = 0; i < 16; ++i) {
    int c = (t >> 6) + i * 4;
    int wo = t & 63;
    size_t g = (((size_t)(n * C + c) * H + h) * W) + w0 + wo;
    out[g] = s_out[wo][c];
  }
}

extern "C" void kernel_launch(void* const* d_in, const int* in_sizes, int n_in,
                              void* d_out, int out_size, void* d_ws, size_t ws_size,
                              hipStream_t stream) {
  const int*   frag   = (const int*)d_in[0];
  const float* alpha  = (const float*)d_in[1];
  const float* ptclds = (const float*)d_in[2];
  float*       out    = (float*)d_out;

  const int P = in_sizes[2] / C;  // 100000
  const size_t tableBytes = (size_t)P * C * sizeof(__half);  // 12.8 MB

  if (ws_size >= tableBytes) {
    __half2* ptT = (__half2*)d_ws;
    const int PB = (P + 255) / 256;  // 391
    transpose_pt<<<2 * PB, 256, 0, stream>>>(ptclds, ptT, P, PB);
    compositor_wide<<<2 * N * H, 256, 0, stream>>>(frag, alpha, ptT, out, P);
  } else {
    compositor_fallback<<<N * H * (W / 64), 256, 0, stream>>>(frag, alpha,
                                                              ptclds, out, P);
  }
}